// Round 5
// baseline (428.552 us; speedup 1.0000x reference)
//
#include <hip/hip_runtime.h>
#include <hip/hip_bf16.h>
#include <math.h>

// Problem constants
#define CCd     0.01
#define SCd     0.1         // sqrt(C)
#define MAXNRMd 9.99        // (1-0.001)/sqrt(C)
#define MINNd   1e-5
#define DD      1024
#define NK      25          // K*N support rows
#define NQ      75          // K*Q query rows
#define NROWS   100
#define KCLS    5
#define NAUG    40

__device__ __forceinline__ double wave_reduce_d(double v){
#pragma unroll
  for (int o = 32; o > 0; o >>= 1) v += __shfl_xor(v, o);
  return v;
}

// all 1024 threads must call; returns full-block sum to every thread
__device__ __forceinline__ double block_sum_d(double v, double* red){
  v = wave_reduce_d(v);
  const int wv = threadIdx.x >> 6, ln = threadIdx.x & 63;
  __syncthreads();                  // protect red from previous use
  if (ln == 0) red[wv] = v;
  __syncthreads();
  double s = 0.0;
#pragma unroll
  for (int i = 0; i < 16; i++) s += red[i];
  return s;
}

__device__ __forceinline__ double hyp_dist_d(double xy, double x2, double y2){
  double a    = 1.0 - 2.0*CCd*xy + CCd*y2;
  double b    = 1.0 - CCd*x2;
  double num2 = a*a*x2 + b*b*y2 - 2.0*a*b*xy;
  double den  = 1.0 - 2.0*CCd*xy + CCd*CCd*x2*y2;
  double nrm  = sqrt(fmax(num2, 0.0)) / fmax(den, MINNd);
  double z    = SCd * nrm;
  z = fmin(fmax(z, -1.0 + MINNd), 1.0 - MINNd);
  // (2/sc) * artanh(z) = 10*log((1+z)/(1-z))
  return 10.0 * log((1.0 + z) / (1.0 - z));
}

__global__ __launch_bounds__(1024)
void hpr_wn_kernel(const float* __restrict__ feat, const int* __restrict__ label,
                   const float* __restrict__ noise, float* __restrict__ out,
                   float* __restrict__ ws)
{
  const int tid  = threadIdx.x;
  const int wave = tid >> 6;
  const int lane = tid & 63;

  float* P      = ws;                 // [100][1024] projected poincare points (fp32 storage)
  float* protoP = ws + NROWS*DD;      // [5][1024]
  float* protoN = protoP + KCLS*DD;   // [5][1024]

  __shared__ double p2s[NROWS];             // ||P_row||^2 (analytic, double)
  __shared__ double proto2s[KCLS], protoN2s[KCLS];
  __shared__ double distS[NQ*KCLS], distN[NQ*KCLS];
  __shared__ int    predS[NQ];
  __shared__ double wA[80], wM[80];         // per-class masked-mean coefs
  __shared__ double scal[8];
  __shared__ double spS[DD], stdS[DD];
  __shared__ double coefSj[NAUG], coefVj[NAUG], lamJ[NAUG];
  __shared__ double supC[8];
  __shared__ double red[16];
  __shared__ double lossPart[80];

  // ---------- Phase 1: expmap0 + project for all 100 rows ----------
  for (int r = wave; r < NROWS; r += 16) {
    const float4* s4 = reinterpret_cast<const float4*>(feat + r*DD);
    float4 v[4]; double ss = 0.0;
#pragma unroll
    for (int k = 0; k < 4; k++){
      v[k] = s4[lane + 64*k];
      ss += (double)v[k].x*v[k].x + (double)v[k].y*v[k].y
          + (double)v[k].z*v[k].z + (double)v[k].w*v[k].w;
    }
    ss = wave_reduce_d(ss);
    double un = fmax(sqrt(ss), MINNd);
    double t  = tanh(SCd*un);
    double na = t * 10.0;            // ||expmap0(u)||
    double factor, pn;
    if (na > MAXNRMd) { factor = MAXNRMd/un; pn = MAXNRMd; }
    else              { factor = t/(SCd*un); pn = na; }
    float4* d4 = reinterpret_cast<float4*>(P + r*DD);
#pragma unroll
    for (int k = 0; k < 4; k++){
      float4 o4;
      o4.x = (float)(v[k].x*factor); o4.y = (float)(v[k].y*factor);
      o4.z = (float)(v[k].z*factor); o4.w = (float)(v[k].w*factor);
      d4[lane + 64*k] = o4;
    }
    if (lane == 0) p2s[r] = pn*pn;
  }
  __syncthreads();

  // ---------- Phase 2: proto_p = poincare mean of each class's 5 support ----------
  if (wave < KCLS) {
    const int c = wave;
    double la[5], wsum = 0.0;        // la = lam*a ; wsum = sum lam
#pragma unroll
    for (int i = 0; i < 5; i++){
      double pp = p2s[c*5+i];
      double a  = 2.0/(1.0 + CCd*pp);
      double k2 = a*a*pp;
      double l  = 1.0/sqrt(fmax(1.0 - CCd*k2, MINNd));
      la[i] = l*a; wsum += l;
    }
    double ss = 0.0; double mk[16];
#pragma unroll
    for (int k = 0; k < 16; k++){
      int d = lane + 64*k;
      double s = 0.0;
#pragma unroll
      for (int i = 0; i < 5; i++) s += la[i]*(double)P[(c*5+i)*DD + d];
      s /= wsum;
      mk[k] = s; ss += s*s;
    }
    ss = wave_reduce_d(ss);
    double sf = 1.0/(1.0 + sqrt(fmax(1.0 - CCd*ss, 0.0)));
#pragma unroll
    for (int k = 0; k < 16; k++) protoP[c*DD + lane + 64*k] = (float)(mk[k]*sf);
    if (lane == 0) proto2s[c] = ss*sf*sf;
  }
  __syncthreads();

  // ---------- Phase 3: dist(queries_p, proto_p) ----------
  for (int p = wave; p < NQ*KCLS; p += 16) {
    const int q = p / KCLS, c = p % KCLS;
    const float* xq = P + (NK+q)*DD;
    const float* yc = protoP + c*DD;
    double dot = 0.0;
#pragma unroll
    for (int k = 0; k < 16; k++){ int d = lane + 64*k; dot += (double)xq[d]*(double)yc[d]; }
    dot = wave_reduce_d(dot);
    if (lane == 0) distS[q*KCLS + c] = hyp_dist_d(dot, p2s[NK+q], proto2s[c]);
  }
  __syncthreads();

  // ---------- Phase 4: pred (argmax of -dist => first min of dist) ----------
  if (tid < NQ){
    double best = distS[tid*KCLS]; int bi = 0;
#pragma unroll
    for (int c = 1; c < KCLS; c++){
      double dv = distS[tid*KCLS + c];
      if (dv < best){ best = dv; bi = c; }
    }
    predS[tid] = bi;
  }
  __syncthreads();

  // ---------- Phase 5: per-class augmentation + new prototype ----------
  for (int c = 0; c < KCLS; c++){
    // 5a: 80-point masked weights
    if (tid < 80){
      int row; double m;
      if (tid < 5){ row = c*5 + tid; m = 1.0; }
      else        { row = NK + (tid-5); m = (predS[tid-5] == c) ? 1.0 : 0.0; }
      double pp = p2s[row];
      double a  = 2.0/(1.0 + CCd*pp);
      double k2 = a*a*pp;
      double l  = 1.0/sqrt(fmax(1.0 - CCd*k2, MINNd));
      wA[tid] = m*l*a;   // coef for P[row] in weighted-k sum
      wM[tid] = m;
    }
    __syncthreads();
    if (tid == 0){
      double wsum = 0.0, cnt = 0.0;
      for (int i = 0; i < 80; i++){
        cnt += wM[i];
        int row = (i < 5) ? c*5 + i : NK + (i-5);
        double pp = p2s[row];
        double a  = 2.0/(1.0 + CCd*pp);
        double k2 = a*a*pp;
        double l  = 1.0/sqrt(fmax(1.0 - CCd*k2, MINNd));
        wsum += wM[i]*l;
      }
      scal[0] = wsum; scal[1] = cnt;
    }
    __syncthreads();
    const double wsum = scal[0], cnt = scal[1];

    // 5b: per-dim weighted mean (s_p), mu, var/std
    {
      const int d = tid;
      double mkd = 0.0, mud = 0.0, sqd = 0.0;
      for (int i = 0; i < 80; i++){
        int row = (i < 5) ? c*5 + i : NK + (i-5);
        mkd += wA[i] * (double)P[row*DD + d];
        double e = (double)feat[row*DD + d];
        mud += wM[i]*e;
        sqd += wM[i]*e*e;
      }
      mkd /= wsum;
      mud /= cnt;
      double var = (sqd - cnt*mud*mud) / (cnt - 1.0);
      stdS[d] = sqrt(fmax(var, 0.0));
      double mk2 = block_sum_d(mkd*mkd, red);
      double sf  = 1.0/(1.0 + sqrt(fmax(1.0 - CCd*mk2, 0.0)));
      spS[d] = mkd*sf;
      if (tid == 0) scal[2] = mk2*sf*sf;   // ||s_p||^2
    }
    __syncthreads();
    const double sp2  = scal[2];
    const double lamx = 2.0/fmax(1.0 - CCd*sp2, MINNd);
    const double ptf  = 1.0 - CCd*sp2;     // ptransp0 factor == mobius B

    // 5c: per noise row j: two reductions -> closed-form ex coefficients
    for (int j = wave; j < NAUG; j += 16){
      const float* nzr = noise + (c*NAUG + j)*DD;
      double s_un2 = 0.0, s_dot = 0.0;
#pragma unroll
      for (int k = 0; k < 16; k++){
        int d = lane + 64*k;
        double v = (double)nzr[d]*stdS[d];
        s_un2 += v*v;
        s_dot += v*spS[d];
      }
#pragma unroll
      for (int o = 32; o > 0; o >>= 1){
        s_un2 += __shfl_xor(s_un2, o);
        s_dot += __shfl_xor(s_dot, o);
      }
      if (lane == 0){
        double unv = sqrt(s_un2);              // ||v||
        double unp = fmax(ptf*unv, MINNd);     // ||pt||
        double g0  = tanh(SCd*lamx*unp*0.5)/(SCd*unp);
        double g   = g0*ptf;                   // second = g * v
        double y2  = g*g*s_un2;
        double xy  = g*s_dot;
        double A   = 1.0 + 2.0*CCd*xy + CCd*y2;
        double B   = ptf;
        double den = fmax(1.0 + 2.0*CCd*xy + CCd*CCd*sp2*y2, MINNd);
        // ex = (A*sp + B*g*v)/den
        double ex2 = (A*A*sp2 + 2.0*A*B*g*s_dot + B*B*g*g*s_un2)/(den*den);
        double ae  = 2.0/(1.0 + CCd*ex2);
        double k2e = ae*ae*ex2;
        double le  = 1.0/sqrt(fmax(1.0 - CCd*k2e, MINNd));
        coefSj[j] = le*ae*A/den;
        coefVj[j] = le*ae*B*g/den;
        lamJ[j]   = le;
      }
    }
    __syncthreads();
    if (tid == 0){
      double lsum = 0.0, sS = 0.0;
#pragma unroll
      for (int i = 0; i < 5; i++){
        double pp = p2s[c*5+i];
        double a  = 2.0/(1.0 + CCd*pp);
        double k2 = a*a*pp;
        double l  = 1.0/sqrt(fmax(1.0 - CCd*k2, MINNd));
        supC[i] = l*a; lsum += l;
      }
      for (int j = 0; j < NAUG; j++){ lsum += lamJ[j]; sS += coefSj[j]; }
      scal[3] = lsum; scal[4] = sS;
    }
    __syncthreads();
    const double lamsum = scal[3], sumS = scal[4];

    // 5d: assemble 45-point poincare mean per dim
    {
      const int d = tid;
      double val = sumS * spS[d];
#pragma unroll
      for (int i = 0; i < 5; i++) val += supC[i]*(double)P[(c*5+i)*DD + d];
      double nacc = 0.0;
      for (int j = 0; j < NAUG; j++) nacc += coefVj[j]*(double)noise[(c*NAUG + j)*DD + d];
      val += stdS[d]*nacc;
      val /= lamsum;
      double mk2 = block_sum_d(val*val, red);
      double sf  = 1.0/(1.0 + sqrt(fmax(1.0 - CCd*mk2, 0.0)));
      protoN[c*DD + d] = (float)(val*sf);
      if (tid == 0) protoN2s[c] = mk2*sf*sf;
    }
    __syncthreads();
  }

  // ---------- Phase 6: dist_new(queries_p, proto_new) ----------
  for (int p = wave; p < NQ*KCLS; p += 16) {
    const int q = p / KCLS, c = p % KCLS;
    const float* xq = P + (NK+q)*DD;
    const float* yc = protoN + c*DD;
    double dot = 0.0;
#pragma unroll
    for (int k = 0; k < 16; k++){ int d = lane + 64*k; dot += (double)xq[d]*(double)yc[d]; }
    dot = wave_reduce_d(dot);
    if (lane == 0) distN[q*KCLS + c] = hyp_dist_d(dot, p2s[NK+q], protoN2s[c]);
  }
  __syncthreads();

  // ---------- Phase 7: softmax / double log_softmax / loss ----------
  if (tid < NQ){
    const int q = tid;
    // y_pred = softmax(-dist_new)
    double v[5]; double mx = -1e300;
#pragma unroll
    for (int c = 0; c < 5; c++){ v[c] = -distN[q*5+c]; mx = fmax(mx, v[c]); }
    double se = 0.0;
#pragma unroll
    for (int c = 0; c < 5; c++){ v[c] = exp(v[c]-mx); se += v[c]; }
    double inv = 1.0/se;
#pragma unroll
    for (int c = 0; c < 5; c++) out[q*5+c] = (float)(v[c]*inv);

    // log_p_y = log_softmax(-dist); ll = log_softmax(log_p_y)
    double u[5]; mx = -1e300;
#pragma unroll
    for (int c = 0; c < 5; c++){ u[c] = -distS[q*5+c]; mx = fmax(mx, u[c]); }
    double s1 = 0.0;
#pragma unroll
    for (int c = 0; c < 5; c++) s1 += exp(u[c]-mx);
    double lse1 = mx + log(s1);
#pragma unroll
    for (int c = 0; c < 5; c++) u[c] -= lse1;
    double mx2 = -1e300;
#pragma unroll
    for (int c = 0; c < 5; c++) mx2 = fmax(mx2, u[c]);
    double s2 = 0.0;
#pragma unroll
    for (int c = 0; c < 5; c++) s2 += exp(u[c]-mx2);
    double lse2 = mx2 + log(s2);
    int lb = label[NQ + q];           // label[1][q]
    lossPart[q] = u[lb] - lse2;
  }
  __syncthreads();
  if (tid == 0){
    double s = 0.0;
    for (int q = 0; q < NQ; q++) s += lossPart[q];
    out[NQ*KCLS] = (float)(-s/75.0);
  }
}

extern "C" void kernel_launch(void* const* d_in, const int* in_sizes, int n_in,
                              void* d_out, int out_size, void* d_ws, size_t ws_size,
                              hipStream_t stream) {
  const float* feat  = (const float*)d_in[0];
  const int*   label = (const int*)d_in[1];
  const float* noise = (const float*)d_in[2];
  float* out = (float*)d_out;
  float* ws  = (float*)d_ws;
  hipLaunchKernelGGL(hpr_wn_kernel, dim3(1), dim3(1024), 0, stream,
                     feat, label, noise, out, ws);
}

// Round 6
// 119.903 us; speedup vs baseline: 3.5742x; 3.5742x over previous
//
#include <hip/hip_runtime.h>
#include <hip/hip_bf16.h>
#include <math.h>

// Problem constants
#define CCd     0.01
#define SCd     0.1         // sqrt(C)
#define MAXNRMd 9.99        // (1-0.001)/sqrt(C)
#define MINNd   1e-5
#define DD      1024
#define NK      25          // K*N support rows
#define NQ      75          // K*Q query rows
#define NROWS   100
#define KCLS    5
#define NAUG    40

__device__ __forceinline__ double wave_reduce_d(double v){
#pragma unroll
  for (int o = 32; o > 0; o >>= 1) v += __shfl_xor(v, o);
  return v;
}

__device__ __forceinline__ double hyp_dist_d(double xy, double x2, double y2){
  double a    = 1.0 - 2.0*CCd*xy + CCd*y2;
  double b    = 1.0 - CCd*x2;
  double num2 = a*a*x2 + b*b*y2 - 2.0*a*b*xy;
  double den  = 1.0 - 2.0*CCd*xy + CCd*CCd*x2*y2;
  double nrm  = sqrt(fmax(num2, 0.0)) / fmax(den, MINNd);
  double z    = SCd * nrm;
  z = fmin(fmax(z, -1.0 + MINNd), 1.0 - MINNd);
  return 10.0 * log((1.0 + z) / (1.0 - z));   // (2/sc)*artanh(z)
}

// ---------- K1: expmap0 + project, one block per row ----------
__global__ __launch_bounds__(256)
void k_expmap(const float* __restrict__ feat, float* __restrict__ P,
              double* __restrict__ p2d){
  const int r = blockIdx.x, t = threadIdx.x;
  const float4 v = reinterpret_cast<const float4*>(feat + r*DD)[t];
  double ss = (double)v.x*v.x + (double)v.y*v.y + (double)v.z*v.z + (double)v.w*v.w;
  __shared__ double red[4];
  ss = wave_reduce_d(ss);
  if ((t & 63) == 0) red[t >> 6] = ss;
  __syncthreads();
  ss = red[0] + red[1] + red[2] + red[3];
  double un = fmax(sqrt(ss), MINNd);
  double th = tanh(SCd*un);
  double na = th * 10.0;                   // ||expmap0(u)||
  double factor, pn;
  if (na > MAXNRMd) { factor = MAXNRMd/un; pn = MAXNRMd; }
  else              { factor = th/(SCd*un); pn = na; }
  float4 o;
  o.x = (float)(v.x*factor); o.y = (float)(v.y*factor);
  o.z = (float)(v.z*factor); o.w = (float)(v.w*factor);
  reinterpret_cast<float4*>(P + r*DD)[t] = o;
  if (t == 0) p2d[r] = pn*pn;
}

// ---------- K2: proto_p per class, one block per class ----------
__global__ __launch_bounds__(1024)
void k_proto(const float* __restrict__ P, const double* __restrict__ p2d,
             float* __restrict__ protoP, double* __restrict__ proto2d){
  const int c = blockIdx.x, t = threadIdx.x;
  double la[5], wsum = 0.0;
#pragma unroll
  for (int i = 0; i < 5; i++){
    double pp = p2d[c*5+i];
    double a  = 2.0/(1.0 + CCd*pp);
    double k2 = a*a*pp;
    double l  = 1.0/sqrt(fmax(1.0 - CCd*k2, MINNd));
    la[i] = l*a; wsum += l;
  }
  double s = 0.0;
#pragma unroll
  for (int i = 0; i < 5; i++) s += la[i]*(double)P[(c*5+i)*DD + t];
  s /= wsum;
  __shared__ double red[16];
  double ss = wave_reduce_d(s*s);
  if ((t & 63) == 0) red[t >> 6] = ss;
  __syncthreads();
  ss = 0.0;
#pragma unroll
  for (int i = 0; i < 16; i++) ss += red[i];
  double sf = 1.0/(1.0 + sqrt(fmax(1.0 - CCd*ss, 0.0)));
  protoP[c*DD + t] = (float)(s*sf);
  if (t == 0) proto2d[c] = ss*sf*sf;
}

// ---------- K3: dist(queries, protoP) + pred, one block per query ----------
__global__ __launch_bounds__(256)
void k_dist1(const float* __restrict__ P, const float* __restrict__ protoP,
             const double* __restrict__ p2d, const double* __restrict__ proto2d,
             double* __restrict__ distS, int* __restrict__ predS){
  const int q = blockIdx.x, t = threadIdx.x;
  const float* xq = P + (NK+q)*DD;
  double acc[5] = {0,0,0,0,0};
#pragma unroll
  for (int k = 0; k < 4; k++){
    int d = t + 256*k;
    double x = (double)xq[d];
#pragma unroll
    for (int c = 0; c < 5; c++) acc[c] += x*(double)protoP[c*DD + d];
  }
  __shared__ double red[4][5];
#pragma unroll
  for (int c = 0; c < 5; c++) acc[c] = wave_reduce_d(acc[c]);
  if ((t & 63) == 0){
#pragma unroll
    for (int c = 0; c < 5; c++) red[t >> 6][c] = acc[c];
  }
  __syncthreads();
  if (t == 0){
    double x2 = p2d[NK+q];
    double best = 1e300; int bi = 0;
#pragma unroll
    for (int c = 0; c < 5; c++){
      double dot = red[0][c] + red[1][c] + red[2][c] + red[3][c];
      double dv  = hyp_dist_d(dot, x2, proto2d[c]);
      distS[q*5 + c] = dv;
      if (dv < best){ best = dv; bi = c; }   // first-min == argmax(-dist)
    }
    predS[q] = bi;
  }
}

// ---------- K4: per-class augmentation + new prototype, one block per class ----------
__global__ __launch_bounds__(1024)
void k_aug(const float* __restrict__ feat, const float* __restrict__ noise,
           const float* __restrict__ P, const double* __restrict__ p2d,
           const int* __restrict__ predS,
           float* __restrict__ protoN, double* __restrict__ protoN2d){
  const int c = blockIdx.x, t = threadIdx.x;
  const int wave = t >> 6, lane = t & 63;
  __shared__ double wA[80], wL[80], wM[80];
  __shared__ int    rows[80];
  __shared__ double scal[8];
  __shared__ double spS[DD], stdS[DD];
  __shared__ double coefSj[NAUG], coefVj[NAUG], lamJ[NAUG];
  __shared__ double red[16];

  // 5a: 80-point masked weights
  if (t < 80){
    int row; double m;
    if (t < 5){ row = c*5 + t; m = 1.0; }
    else      { row = NK + (t-5); m = (predS[t-5] == c) ? 1.0 : 0.0; }
    rows[t] = row;
    double pp = p2d[row];
    double a  = 2.0/(1.0 + CCd*pp);
    double k2 = a*a*pp;
    double l  = 1.0/sqrt(fmax(1.0 - CCd*k2, MINNd));
    wA[t] = m*l*a; wL[t] = m*l; wM[t] = m;
  }
  __syncthreads();
  if (t == 0){
    double wsum = 0.0, cnt = 0.0;
    for (int i = 0; i < 80; i++){ wsum += wL[i]; cnt += wM[i]; }
    scal[0] = wsum; scal[1] = cnt;
  }
  __syncthreads();
  const double wsum = scal[0], cnt = scal[1];

  // 5b: per-dim weighted mean (s_p), mu, var/std
  {
    const int d = t;
    double mkd = 0.0, mud = 0.0, sqd = 0.0;
    for (int i = 0; i < 80; i++){
      int row = rows[i];
      mkd += wA[i]*(double)P[row*DD + d];
      double e = (double)feat[row*DD + d];
      mud += wM[i]*e;
      sqd += wM[i]*e*e;
    }
    mkd /= wsum;
    mud /= cnt;
    double var = (sqd - cnt*mud*mud)/(cnt - 1.0);
    stdS[d] = sqrt(fmax(var, 0.0));
    double s = wave_reduce_d(mkd*mkd);
    if (lane == 0) red[wave] = s;
    __syncthreads();
    double mk2 = 0.0;
#pragma unroll
    for (int i = 0; i < 16; i++) mk2 += red[i];
    double sf = 1.0/(1.0 + sqrt(fmax(1.0 - CCd*mk2, 0.0)));
    spS[d] = mkd*sf;
    if (t == 0) scal[2] = mk2*sf*sf;     // ||s_p||^2
  }
  __syncthreads();
  const double sp2  = scal[2];
  const double lamx = 2.0/fmax(1.0 - CCd*sp2, MINNd);
  const double ptf  = 1.0 - CCd*sp2;     // ptransp0 factor == mobius B

  // 5c: per noise row j -> closed-form ex coefficients
  for (int j = wave; j < NAUG; j += 16){
    const float* nzr = noise + (c*NAUG + j)*DD;
    double s_un2 = 0.0, s_dot = 0.0;
#pragma unroll
    for (int k = 0; k < 16; k++){
      int d = lane + 64*k;
      double v = (double)nzr[d]*stdS[d];
      s_un2 += v*v;
      s_dot += v*spS[d];
    }
#pragma unroll
    for (int o = 32; o > 0; o >>= 1){
      s_un2 += __shfl_xor(s_un2, o);
      s_dot += __shfl_xor(s_dot, o);
    }
    if (lane == 0){
      double unv = sqrt(s_un2);              // ||v||
      double unp = fmax(ptf*unv, MINNd);     // ||pt||
      double g0  = tanh(SCd*lamx*unp*0.5)/(SCd*unp);
      double g   = g0*ptf;                   // second = g * v
      double y2  = g*g*s_un2;
      double xy  = g*s_dot;
      double A   = 1.0 + 2.0*CCd*xy + CCd*y2;
      double B   = ptf;
      double den = fmax(1.0 + 2.0*CCd*xy + CCd*CCd*sp2*y2, MINNd);
      double ex2 = (A*A*sp2 + 2.0*A*B*g*s_dot + B*B*g*g*s_un2)/(den*den);
      double ae  = 2.0/(1.0 + CCd*ex2);
      double k2e = ae*ae*ex2;
      double le  = 1.0/sqrt(fmax(1.0 - CCd*k2e, MINNd));
      coefSj[j] = le*ae*A/den;
      coefVj[j] = le*ae*B*g/den;
      lamJ[j]   = le;
    }
  }
  __syncthreads();
  if (t == 0){
    double lsum = 0.0, sS = 0.0;
#pragma unroll
    for (int i = 0; i < 5; i++){
      double pp = p2d[c*5+i];
      double a  = 2.0/(1.0 + CCd*pp);
      double k2 = a*a*pp;
      double l  = 1.0/sqrt(fmax(1.0 - CCd*k2, MINNd));
      lsum += l;
    }
    for (int j = 0; j < NAUG; j++){ lsum += lamJ[j]; sS += coefSj[j]; }
    scal[3] = lsum; scal[4] = sS;
  }
  __syncthreads();
  const double lamsum = scal[3], sumS = scal[4];

  // 5d: assemble 45-point poincare mean per dim
  {
    const int d = t;
    double val = sumS*spS[d];
#pragma unroll
    for (int i = 0; i < 5; i++) val += wA[i]*(double)P[(c*5+i)*DD + d];  // wA[i]=l*a for support (m=1)
    double nacc = 0.0;
    for (int j = 0; j < NAUG; j++) nacc += coefVj[j]*(double)noise[(c*NAUG + j)*DD + d];
    val += stdS[d]*nacc;
    val /= lamsum;
    double s = wave_reduce_d(val*val);
    if (lane == 0) red[wave] = s;
    __syncthreads();
    double mk2 = 0.0;
#pragma unroll
    for (int i = 0; i < 16; i++) mk2 += red[i];
    double sf = 1.0/(1.0 + sqrt(fmax(1.0 - CCd*mk2, 0.0)));
    protoN[c*DD + d] = (float)(val*sf);
    if (t == 0) protoN2d[c] = mk2*sf*sf;
  }
}

// ---------- K5: dist_new + y_pred softmax + per-query loss term ----------
__global__ __launch_bounds__(256)
void k_dist2(const float* __restrict__ P, const float* __restrict__ protoN,
             const double* __restrict__ p2d, const double* __restrict__ protoN2d,
             const double* __restrict__ distS, const int* __restrict__ label,
             float* __restrict__ out, double* __restrict__ lossQ){
  const int q = blockIdx.x, t = threadIdx.x;
  const float* xq = P + (NK+q)*DD;
  double acc[5] = {0,0,0,0,0};
#pragma unroll
  for (int k = 0; k < 4; k++){
    int d = t + 256*k;
    double x = (double)xq[d];
#pragma unroll
    for (int c = 0; c < 5; c++) acc[c] += x*(double)protoN[c*DD + d];
  }
  __shared__ double red[4][5];
#pragma unroll
  for (int c = 0; c < 5; c++) acc[c] = wave_reduce_d(acc[c]);
  if ((t & 63) == 0){
#pragma unroll
    for (int c = 0; c < 5; c++) red[t >> 6][c] = acc[c];
  }
  __syncthreads();
  if (t == 0){
    double x2 = p2d[NK+q];
    double v[5]; double mx = -1e300;
#pragma unroll
    for (int c = 0; c < 5; c++){
      double dot = red[0][c] + red[1][c] + red[2][c] + red[3][c];
      v[c] = -hyp_dist_d(dot, x2, protoN2d[c]);
      mx = fmax(mx, v[c]);
    }
    double se = 0.0;
#pragma unroll
    for (int c = 0; c < 5; c++){ v[c] = exp(v[c]-mx); se += v[c]; }
    double inv = 1.0/se;
#pragma unroll
    for (int c = 0; c < 5; c++) out[q*5 + c] = (float)(v[c]*inv);

    // ll = log_softmax(log_softmax(-distS)); lossQ = ll[label]
    double u[5]; mx = -1e300;
#pragma unroll
    for (int c = 0; c < 5; c++){ u[c] = -distS[q*5+c]; mx = fmax(mx, u[c]); }
    double s1 = 0.0;
#pragma unroll
    for (int c = 0; c < 5; c++) s1 += exp(u[c]-mx);
    double lse1 = mx + log(s1);
#pragma unroll
    for (int c = 0; c < 5; c++) u[c] -= lse1;
    double mx2 = -1e300;
#pragma unroll
    for (int c = 0; c < 5; c++) mx2 = fmax(mx2, u[c]);
    double s2 = 0.0;
#pragma unroll
    for (int c = 0; c < 5; c++) s2 += exp(u[c]-mx2);
    double lse2 = mx2 + log(s2);
    lossQ[q] = u[label[NQ + q]] - lse2;
  }
}

// ---------- K6: final loss reduction ----------
__global__ __launch_bounds__(128)
void k_loss(const double* __restrict__ lossQ, float* __restrict__ out){
  const int t = threadIdx.x;
  double v = (t < NQ) ? lossQ[t] : 0.0;
  v = wave_reduce_d(v);
  __shared__ double red[2];
  if ((t & 63) == 0) red[t >> 6] = v;
  __syncthreads();
  if (t == 0) out[NQ*KCLS] = (float)(-(red[0]+red[1])/75.0);
}

extern "C" void kernel_launch(void* const* d_in, const int* in_sizes, int n_in,
                              void* d_out, int out_size, void* d_ws, size_t ws_size,
                              hipStream_t stream) {
  const float* feat  = (const float*)d_in[0];
  const int*   label = (const int*)d_in[1];
  const float* noise = (const float*)d_in[2];
  float* out = (float*)d_out;

  // ws layout (offset of doubles is 110*1024*4 = 450560 B, 8-aligned)
  float*  P        = (float*)d_ws;
  float*  protoP   = P + NROWS*DD;
  float*  protoN   = protoP + KCLS*DD;
  double* p2d      = (double*)(protoN + KCLS*DD);
  double* proto2d  = p2d + NROWS;
  double* protoN2d = proto2d + KCLS;
  double* distS    = protoN2d + KCLS;
  double* lossQ    = distS + NQ*KCLS;
  int*    predS    = (int*)(lossQ + NQ);

  k_expmap<<<NROWS, 256, 0, stream>>>(feat, P, p2d);
  k_proto <<<KCLS, 1024, 0, stream>>>(P, p2d, protoP, proto2d);
  k_dist1 <<<NQ, 256, 0, stream>>>(P, protoP, p2d, proto2d, distS, predS);
  k_aug   <<<KCLS, 1024, 0, stream>>>(feat, noise, P, p2d, predS, protoN, protoN2d);
  k_dist2 <<<NQ, 256, 0, stream>>>(P, protoN, p2d, protoN2d, distS, label, out, lossQ);
  k_loss  <<<1, 128, 0, stream>>>(lossQ, out);
}

// Round 7
// 98.292 us; speedup vs baseline: 4.3600x; 1.2199x over previous
//
#include <hip/hip_runtime.h>
#include <hip/hip_bf16.h>
#include <math.h>

// Problem constants
#define CCd     0.01
#define SCd     0.1         // sqrt(C)
#define MAXNRMd 9.99        // (1-0.001)/sqrt(C)
#define MINNd   1e-5
#define DD      1024
#define NK      25          // K*N support rows
#define NQ      75          // K*Q query rows
#define NROWS   100
#define KCLS    5
#define NAUG    40

__device__ __forceinline__ double wave_reduce_d(double v){
#pragma unroll
  for (int o = 32; o > 0; o >>= 1) v += __shfl_xor(v, o);
  return v;
}

__device__ __forceinline__ double hyp_dist_d(double xy, double x2, double y2){
  double a    = 1.0 - 2.0*CCd*xy + CCd*y2;
  double b    = 1.0 - CCd*x2;
  double num2 = a*a*x2 + b*b*y2 - 2.0*a*b*xy;
  double den  = 1.0 - 2.0*CCd*xy + CCd*CCd*x2*y2;
  double nrm  = sqrt(fmax(num2, 0.0)) / fmax(den, MINNd);
  double z    = SCd * nrm;
  z = fmin(fmax(z, -1.0 + MINNd), 1.0 - MINNd);
  return 10.0 * log((1.0 + z) / (1.0 - z));   // (2/sc)*artanh(z)
}

// lam*a and lam from ||p||^2 (k-space conversion weights)
__device__ __forceinline__ void kweights(double pp, double* la, double* l_out){
  double a  = 2.0/(1.0 + CCd*pp);
  double k2 = a*a*pp;
  double l  = 1.0/sqrt(fmax(1.0 - CCd*k2, MINNd));
  *la = l*a; *l_out = l;
}

// ---------- K1: expmap0 + project, one block per row ----------
__global__ __launch_bounds__(256)
void k_expmap(const float* __restrict__ feat, float* __restrict__ P,
              double* __restrict__ p2d){
  const int r = blockIdx.x, t = threadIdx.x;
  const float4 v = reinterpret_cast<const float4*>(feat + r*DD)[t];
  double ss = (double)v.x*v.x + (double)v.y*v.y + (double)v.z*v.z + (double)v.w*v.w;
  __shared__ double red[4];
  ss = wave_reduce_d(ss);
  if ((t & 63) == 0) red[t >> 6] = ss;
  __syncthreads();
  ss = red[0] + red[1] + red[2] + red[3];
  double un = fmax(sqrt(ss), MINNd);
  double th = tanh(SCd*un);
  double na = th * 10.0;                   // ||expmap0(u)||
  double factor, pn;
  if (na > MAXNRMd) { factor = MAXNRMd/un; pn = MAXNRMd; }
  else              { factor = th/(SCd*un); pn = na; }
  float4 o;
  o.x = (float)(v.x*factor); o.y = (float)(v.y*factor);
  o.z = (float)(v.z*factor); o.w = (float)(v.w*factor);
  reinterpret_cast<float4*>(P + r*DD)[t] = o;
  if (t == 0) p2d[r] = pn*pn;
}

// ---------- K2: proto_p per class, one block per class ----------
__global__ __launch_bounds__(1024)
void k_proto(const float* __restrict__ P, const double* __restrict__ p2d,
             float* __restrict__ protoP, double* __restrict__ proto2d){
  const int c = blockIdx.x, t = threadIdx.x;
  double la[5], wsum = 0.0;
#pragma unroll
  for (int i = 0; i < 5; i++){
    double lam;
    kweights(p2d[c*5+i], &la[i], &lam);
    wsum += lam;
  }
  double s = 0.0;
#pragma unroll
  for (int i = 0; i < 5; i++) s += la[i]*(double)P[(c*5+i)*DD + t];
  s /= wsum;
  __shared__ double red[16];
  double ss = wave_reduce_d(s*s);
  if ((t & 63) == 0) red[t >> 6] = ss;
  __syncthreads();
  ss = 0.0;
#pragma unroll
  for (int i = 0; i < 16; i++) ss += red[i];
  double sf = 1.0/(1.0 + sqrt(fmax(1.0 - CCd*ss, 0.0)));
  protoP[c*DD + t] = (float)(s*sf);
  if (t == 0) proto2d[c] = ss*sf*sf;
}

// ---------- K3: dist(queries, protoP) + pred, one block per query ----------
__global__ __launch_bounds__(256)
void k_dist1(const float* __restrict__ P, const float* __restrict__ protoP,
             const double* __restrict__ p2d, const double* __restrict__ proto2d,
             double* __restrict__ distS, int* __restrict__ predS){
  const int q = blockIdx.x, t = threadIdx.x;
  const float* xq = P + (NK+q)*DD;
  double acc[5] = {0,0,0,0,0};
#pragma unroll
  for (int k = 0; k < 4; k++){
    int d = t + 256*k;
    double x = (double)xq[d];
#pragma unroll
    for (int c = 0; c < 5; c++) acc[c] += x*(double)protoP[c*DD + d];
  }
  __shared__ double red[4][5];
#pragma unroll
  for (int c = 0; c < 5; c++) acc[c] = wave_reduce_d(acc[c]);
  if ((t & 63) == 0){
#pragma unroll
    for (int c = 0; c < 5; c++) red[t >> 6][c] = acc[c];
  }
  __syncthreads();
  if (t == 0){
    double x2 = p2d[NK+q];
    double best = 1e300; int bi = 0;
#pragma unroll
    for (int c = 0; c < 5; c++){
      double dot = red[0][c] + red[1][c] + red[2][c] + red[3][c];
      double dv  = hyp_dist_d(dot, x2, proto2d[c]);
      distS[q*5 + c] = dv;
      if (dv < best){ best = dv; bi = c; }   // first-min == argmax(-dist)
    }
    predS[q] = bi;
  }
}

// ---------- K4a: per-(class,dim) masked stats: raw mean_k, std, partial ||mk||^2 ----------
__global__ __launch_bounds__(256)
void k_stats(const float* __restrict__ feat, const float* __restrict__ P,
             const double* __restrict__ p2d, const int* __restrict__ predS,
             double* __restrict__ std_g, double* __restrict__ mkr_g,
             double* __restrict__ mk2part){
  const int c = blockIdx.x >> 2, chunk = blockIdx.x & 3, t = threadIdx.x;
  __shared__ double wA[80], wL[80], wM[80], scal[2], red[4];
  __shared__ int rows[80];
  if (t < 80){
    int row; double m;
    if (t < 5){ row = c*5 + t; m = 1.0; }
    else      { row = NK + (t-5); m = (predS[t-5] == c) ? 1.0 : 0.0; }
    rows[t] = row;
    double la, l; kweights(p2d[row], &la, &l);
    wA[t] = m*la; wL[t] = m*l; wM[t] = m;
  }
  __syncthreads();
  if (t == 0){
    double wsum = 0.0, cnt = 0.0;
    for (int i = 0; i < 80; i++){ wsum += wL[i]; cnt += wM[i]; }
    scal[0] = wsum; scal[1] = cnt;
  }
  __syncthreads();
  const double wsum = scal[0], cnt = scal[1];
  const int d = chunk*256 + t;
  double mkd = 0.0, mud = 0.0, sqd = 0.0;
  for (int i = 0; i < 80; i++){
    int row = rows[i];
    mkd += wA[i]*(double)P[row*DD + d];
    double e = (double)feat[row*DD + d];
    mud += wM[i]*e;
    sqd += wM[i]*e*e;
  }
  mkd /= wsum;
  mud /= cnt;
  double var = (sqd - cnt*mud*mud)/(cnt - 1.0);
  std_g[c*DD + d] = sqrt(fmax(var, 0.0));
  mkr_g[c*DD + d] = mkd;
  double s = wave_reduce_d(mkd*mkd);
  if ((t & 63) == 0) red[t >> 6] = s;
  __syncthreads();
  if (t == 0) mk2part[blockIdx.x] = red[0] + red[1] + red[2] + red[3];
}

// ---------- K4b: per-(class,noise-row) closed-form ex coefficients ----------
__global__ __launch_bounds__(256)
void k_coef(const float* __restrict__ noise, const double* __restrict__ std_g,
            const double* __restrict__ mkr_g, const double* __restrict__ mk2part,
            double* __restrict__ coefS_g, double* __restrict__ coefV_g,
            double* __restrict__ lamJ_g){
  const int j = blockIdx.x, c = blockIdx.y, t = threadIdx.x;
  const float*  nzr = noise + (c*NAUG + j)*DD;
  const double* st  = std_g + c*DD;
  const double* mk  = mkr_g + c*DD;
  double un2 = 0.0, rd = 0.0;
#pragma unroll
  for (int k = 0; k < 4; k++){
    int d = t + 256*k;
    double v = (double)nzr[d]*st[d];
    un2 += v*v;
    rd  += v*mk[d];
  }
  __shared__ double red[4][2];
  un2 = wave_reduce_d(un2);
  rd  = wave_reduce_d(rd);
  if ((t & 63) == 0){ red[t >> 6][0] = un2; red[t >> 6][1] = rd; }
  __syncthreads();
  if (t == 0){
    double s_un2 = red[0][0]+red[1][0]+red[2][0]+red[3][0];
    double rdot  = red[0][1]+red[1][1]+red[2][1]+red[3][1];
    double mk2 = mk2part[c*4+0]+mk2part[c*4+1]+mk2part[c*4+2]+mk2part[c*4+3];
    double sf  = 1.0/(1.0 + sqrt(fmax(1.0 - CCd*mk2, 0.0)));
    double sp2 = mk2*sf*sf;                 // ||s_p||^2
    double lamx = 2.0/fmax(1.0 - CCd*sp2, MINNd);
    double ptf  = 1.0 - CCd*sp2;            // ptransp0 factor == mobius B
    double s_dot = sf*rdot;                 // v . s_p
    double unv = sqrt(s_un2);               // ||v||
    double unp = fmax(ptf*unv, MINNd);      // ||pt||
    double g0  = tanh(SCd*lamx*unp*0.5)/(SCd*unp);
    double g   = g0*ptf;                    // second = g * v
    double y2  = g*g*s_un2;
    double xy  = g*s_dot;
    double A   = 1.0 + 2.0*CCd*xy + CCd*y2;
    double B   = ptf;
    double den = fmax(1.0 + 2.0*CCd*xy + CCd*CCd*sp2*y2, MINNd);
    double ex2 = (A*A*sp2 + 2.0*A*B*g*s_dot + B*B*g*g*s_un2)/(den*den);
    double ae  = 2.0/(1.0 + CCd*ex2);
    double k2e = ae*ae*ex2;
    double le  = 1.0/sqrt(fmax(1.0 - CCd*k2e, MINNd));
    coefS_g[c*NAUG + j] = le*ae*A/den;
    coefV_g[c*NAUG + j] = le*ae*B*g/den;
    lamJ_g[c*NAUG + j]  = le;
  }
}

// ---------- K4c: assemble 45-pt mean per (class,dim); UNSCALED proto + partial ||.||^2 ----------
__global__ __launch_bounds__(256)
void k_asm(const float* __restrict__ noise, const float* __restrict__ P,
           const double* __restrict__ p2d, const double* __restrict__ std_g,
           const double* __restrict__ mkr_g, const double* __restrict__ mk2part,
           const double* __restrict__ coefS_g, const double* __restrict__ coefV_g,
           const double* __restrict__ lamJ_g,
           float* __restrict__ protoNr, double* __restrict__ mk2Np){
  const int c = blockIdx.x >> 2, chunk = blockIdx.x & 3, t = threadIdx.x;
  __shared__ double cV[NAUG], supC[5], scal[3], red[4];
  if (t < NAUG) cV[t] = coefV_g[c*NAUG + t];
  if (t == 0){
    double lsum = 0.0, sS = 0.0;
#pragma unroll
    for (int i = 0; i < 5; i++){
      double la, l; kweights(p2d[c*5+i], &la, &l);
      supC[i] = la; lsum += l;
    }
    for (int j = 0; j < NAUG; j++){ lsum += lamJ_g[c*NAUG+j]; sS += coefS_g[c*NAUG+j]; }
    double mk2 = mk2part[c*4+0]+mk2part[c*4+1]+mk2part[c*4+2]+mk2part[c*4+3];
    double sf  = 1.0/(1.0 + sqrt(fmax(1.0 - CCd*mk2, 0.0)));
    scal[0] = lsum; scal[1] = sS; scal[2] = sf;
  }
  __syncthreads();
  const int d = chunk*256 + t;
  double val = scal[1]*scal[2]*mkr_g[c*DD + d];      // sumS * sp_d
#pragma unroll
  for (int i = 0; i < 5; i++) val += supC[i]*(double)P[(c*5+i)*DD + d];
  double na = 0.0;
  for (int j = 0; j < NAUG; j++) na += cV[j]*(double)noise[(c*NAUG + j)*DD + d];
  val += std_g[c*DD + d]*na;
  val /= scal[0];
  protoNr[c*DD + d] = (float)val;                    // unscaled mean_k
  double s = wave_reduce_d(val*val);
  if ((t & 63) == 0) red[t >> 6] = s;
  __syncthreads();
  if (t == 0) mk2Np[blockIdx.x] = red[0] + red[1] + red[2] + red[3];
}

// ---------- K5: dist_new (scale folded in) + y_pred softmax + per-query loss ----------
__global__ __launch_bounds__(256)
void k_dist2(const float* __restrict__ P, const float* __restrict__ protoNr,
             const double* __restrict__ p2d, const double* __restrict__ mk2Np,
             const double* __restrict__ distS, const int* __restrict__ label,
             float* __restrict__ out, double* __restrict__ lossQ){
  const int q = blockIdx.x, t = threadIdx.x;
  const float* xq = P + (NK+q)*DD;
  double acc[5] = {0,0,0,0,0};
#pragma unroll
  for (int k = 0; k < 4; k++){
    int d = t + 256*k;
    double x = (double)xq[d];
#pragma unroll
    for (int c = 0; c < 5; c++) acc[c] += x*(double)protoNr[c*DD + d];
  }
  __shared__ double red[4][5];
#pragma unroll
  for (int c = 0; c < 5; c++) acc[c] = wave_reduce_d(acc[c]);
  if ((t & 63) == 0){
#pragma unroll
    for (int c = 0; c < 5; c++) red[t >> 6][c] = acc[c];
  }
  __syncthreads();
  if (t == 0){
    double x2 = p2d[NK+q];
    double v[5]; double mx = -1e300;
#pragma unroll
    for (int c = 0; c < 5; c++){
      double mk2N = mk2Np[c*4+0]+mk2Np[c*4+1]+mk2Np[c*4+2]+mk2Np[c*4+3];
      double sfN  = 1.0/(1.0 + sqrt(fmax(1.0 - CCd*mk2N, 0.0)));
      double dot  = sfN*(red[0][c] + red[1][c] + red[2][c] + red[3][c]);
      double y2   = mk2N*sfN*sfN;
      v[c] = -hyp_dist_d(dot, x2, y2);
      mx = fmax(mx, v[c]);
    }
    double se = 0.0;
#pragma unroll
    for (int c = 0; c < 5; c++){ v[c] = exp(v[c]-mx); se += v[c]; }
    double inv = 1.0/se;
#pragma unroll
    for (int c = 0; c < 5; c++) out[q*5 + c] = (float)(v[c]*inv);

    // ll = log_softmax(log_softmax(-distS)); lossQ = ll[label]
    double u[5]; mx = -1e300;
#pragma unroll
    for (int c = 0; c < 5; c++){ u[c] = -distS[q*5+c]; mx = fmax(mx, u[c]); }
    double s1 = 0.0;
#pragma unroll
    for (int c = 0; c < 5; c++) s1 += exp(u[c]-mx);
    double lse1 = mx + log(s1);
#pragma unroll
    for (int c = 0; c < 5; c++) u[c] -= lse1;
    double mx2 = -1e300;
#pragma unroll
    for (int c = 0; c < 5; c++) mx2 = fmax(mx2, u[c]);
    double s2 = 0.0;
#pragma unroll
    for (int c = 0; c < 5; c++) s2 += exp(u[c]-mx2);
    double lse2 = mx2 + log(s2);
    lossQ[q] = u[label[NQ + q]] - lse2;
  }
}

// ---------- K6: final loss reduction ----------
__global__ __launch_bounds__(128)
void k_loss(const double* __restrict__ lossQ, float* __restrict__ out){
  const int t = threadIdx.x;
  double v = (t < NQ) ? lossQ[t] : 0.0;
  v = wave_reduce_d(v);
  __shared__ double red[2];
  if ((t & 63) == 0) red[t >> 6] = v;
  __syncthreads();
  if (t == 0) out[NQ*KCLS] = (float)(-(red[0]+red[1])/75.0);
}

extern "C" void kernel_launch(void* const* d_in, const int* in_sizes, int n_in,
                              void* d_out, int out_size, void* d_ws, size_t ws_size,
                              hipStream_t stream) {
  const float* feat  = (const float*)d_in[0];
  const int*   label = (const int*)d_in[1];
  const float* noise = (const float*)d_in[2];
  float* out = (float*)d_out;

  // ws layout (doubles start at 110*1024*4 = 450560 B, 8-aligned)
  float*  P        = (float*)d_ws;
  float*  protoP   = P + NROWS*DD;
  float*  protoNr  = protoP + KCLS*DD;       // unscaled new prototypes
  double* p2d      = (double*)(protoNr + KCLS*DD);
  double* proto2d  = p2d + NROWS;
  double* distS    = proto2d + KCLS;
  double* lossQ    = distS + NQ*KCLS;
  double* std_g    = lossQ + NQ;
  double* mkr_g    = std_g + KCLS*DD;
  double* mk2part  = mkr_g + KCLS*DD;
  double* coefS_g  = mk2part + 4*KCLS;
  double* coefV_g  = coefS_g + KCLS*NAUG;
  double* lamJ_g   = coefV_g + KCLS*NAUG;
  double* mk2Np    = lamJ_g + KCLS*NAUG;
  int*    predS    = (int*)(mk2Np + 4*KCLS);

  k_expmap<<<NROWS, 256, 0, stream>>>(feat, P, p2d);
  k_proto <<<KCLS, 1024, 0, stream>>>(P, p2d, protoP, proto2d);
  k_dist1 <<<NQ, 256, 0, stream>>>(P, protoP, p2d, proto2d, distS, predS);
  k_stats <<<4*KCLS, 256, 0, stream>>>(feat, P, p2d, predS, std_g, mkr_g, mk2part);
  k_coef  <<<dim3(NAUG, KCLS), 256, 0, stream>>>(noise, std_g, mkr_g, mk2part,
                                                 coefS_g, coefV_g, lamJ_g);
  k_asm   <<<4*KCLS, 256, 0, stream>>>(noise, P, p2d, std_g, mkr_g, mk2part,
                                       coefS_g, coefV_g, lamJ_g, protoNr, mk2Np);
  k_dist2 <<<NQ, 256, 0, stream>>>(P, protoNr, p2d, mk2Np, distS, label, out, lossQ);
  k_loss  <<<1, 128, 0, stream>>>(lossQ, out);
}